// Round 17
// baseline (158.744 us; speedup 1.0000x reference)
//
#include <hip/hip_runtime.h>
#include <hip/hip_bf16.h>
#include <math.h>

#define NCHUNK 9
#define BM 128
#define NTHR 512
#define PREPB ((NCHUNK * 128 * 128) / 256)  // 576 Bsw blocks
#define PHA 256        // phase-A binning blocks
#define PERBK 48       // per-(block,bucket) capacity: mean 16, +8 sigma
#define NBUKMAX 512    // LDS counter bound (N <= 131072)

typedef __attribute__((ext_vector_type(4))) float f32x4;
typedef __attribute__((ext_vector_type(8))) short bf16x8;
typedef unsigned int u32;
typedef unsigned long long u64;

__device__ __forceinline__ unsigned short f2bf(float f) {
    u32 u = __builtin_bit_cast(u32, f);
    u32 r = (u + 0x7FFFu + ((u >> 16) & 1u)) >> 16;
    return (unsigned short)r;
}

__device__ __forceinline__ float siluf(float x) {
    return x / (1.0f + __expf(-x));
}

// ---------- merged prep: Bsw build (swizzled) + wa + {hist + LDS-counted binning} ----------
__global__ void k_prep(const float* __restrict__ bw, const float* __restrict__ sw,
                       const float* __restrict__ W, const float* __restrict__ a,
                       unsigned short* __restrict__ Bsw, float* __restrict__ wa,
                       const int* __restrict__ erow, const int* __restrict__ ecol,
                       int* __restrict__ counts, u32* __restrict__ binned,
                       int* __restrict__ pbcnt, int E, int nbuk, int per) {
    int bid = blockIdx.x;
    if (bid < PREPB) {
        int i = bid * 256 + threadIdx.x;
        int j = i & 7;
        int s = (i >> 3) & 15;
        int o = (i >> 7) & 127;
        int c = i >> 14;
        int k = c * 128 + (((s ^ (o & 7)) << 3) | j);
        float v = (k < 128) ? bw[o * 128 + k] : sw[o * 1024 + (k - 128)];
        Bsw[i] = f2bf(v);
        return;
    }
    if (bid == PREPB) {
        int fi = threadIdx.x;
        if (fi < 128) {
            float s1 = 0.f, s2 = 0.f;
            for (int o = 0; o < 128; ++o) {
                float w = W[fi * 128 + o];
                s1 = fmaf(w, a[o], s1);
                s2 = fmaf(w, a[128 + o], s2);
            }
            wa[fi] = s1;
            wa[128 + fi] = s2;
        }
        return;
    }
    // ---- phase-A binning + hist ----
    __shared__ int cnt[NBUKMAX];
    int pb = bid - PREPB - 1;  // 0..PHA-1
    int e0 = pb * per;
    int e1 = min(e0 + per, E);
    for (int i = threadIdx.x; i < nbuk; i += 256) cnt[i] = 0;
    __syncthreads();
    for (int e = e0 + threadIdx.x; e < e1; e += 256) {
        int r = erow[e], c = ecol[e];
        atomicAdd(&counts[r], 1);
        int b = r >> 8;
        int pos = atomicAdd(&cnt[b], 1);
        if (pos < PERBK)  // statistically unreachable (+8 sigma)
            binned[(size_t)b * (PHA * PERBK) + pb * PERBK + pos] =
                ((u32)c << 8) | (u32)(r & 255);
    }
    __syncthreads();
    for (int i = threadIdx.x; i < nbuk; i += 256)
        pbcnt[(size_t)i * PHA + pb] = min(cnt[i], PERBK);
}

// ---------- main node kernel: 128x128 bf16 MFMA GEMM + fused scores + phase-B drain ----------
__global__ __launch_bounds__(NTHR) void k_nodes(const float* __restrict__ h,
                                                const unsigned short* __restrict__ Bsw,
                                                const float* __restrict__ wa,
                                                unsigned short* __restrict__ kanb,
                                                float* __restrict__ s_src,
                                                float* __restrict__ s_dst, int N, int nbn,
                                                const u32* __restrict__ binned,
                                                const int* __restrict__ pbcnt,
                                                const int* __restrict__ offsets,
                                                int* __restrict__ colss) {
    __shared__ unsigned short A_lds[BM * 128];  // 32 KB, XOR-swizzled (reused for C out)
    __shared__ unsigned short B_lds[128 * 128]; // 32 KB, XOR-swizzled (pre-swz global)
    __shared__ int lcur[256];                   // phase-B row cursors (LDS atomics)
    __shared__ int scnt[PHA];                   // phase-B per-segment counts
    const int tid = threadIdx.x;
    const int wid = tid >> 6, lane = tid & 63;

    if (blockIdx.x >= nbn) {  // ---- phase-B bucket-drain blocks ----
        int b = blockIdx.x - nbn;
        int rowbase = b << 8;
        for (int i = tid; i < 256; i += NTHR) {
            int r = rowbase + i;
            lcur[i] = (r < N) ? offsets[r] : 0;
        }
        for (int pb = tid; pb < PHA; pb += NTHR) scnt[pb] = pbcnt[(size_t)b * PHA + pb];
        __syncthreads();
        const u32* src = binned + (size_t)b * (PHA * PERBK);
        for (int pb = wid; pb < PHA; pb += 8) {  // 8 waves, 32 segments each
            int n = scnt[pb];
            if (lane < n) {
                u32 pk = src[pb * PERBK + lane];
                int pos = atomicAdd(&lcur[pk & 255u], 1);  // LDS atomic
                __builtin_nontemporal_store((int)(pk >> 8), &colss[pos]);
            }
        }
        return;
    }

    const int gm0 = blockIdx.x * BM;

    // gen mapping: thread owns (row gm, slot-quad gq) — 4 slots of 8 features
    const int gm = tid >> 2, gq = tid & 3;
    const float* ghr = h + (size_t)min(gm0 + gm, N - 1) * 128;

    const int wm0 = (wid >> 1) * 32;  // wave row offset within tile (8 waves: 4m x 2n)
    const int wn0 = (wid & 1) * 64;   // wave col offset
    f32x4 acc[2][4];
#pragma unroll
    for (int im = 0; im < 2; ++im)
#pragma unroll
        for (int in = 0; in < 4; ++in) acc[im][in] = {0.f, 0.f, 0.f, 0.f};

    f32x4 pf = {0.f, 0.f, 0.f, 0.f};  // spline x for current chunk (valid for chunk>=1)
    for (int chunk = 0; chunk < NCHUNK; ++chunk) {
        // async-stage B chunk (32 KB): each of 8 waves copies its 4 KB segment
        {
            const char* gsrc = (const char*)Bsw + (size_t)chunk * 32768 + wid * 4096 + lane * 16;
            char* ldst = (char*)B_lds + wid * 4096;
#pragma unroll
            for (int i = 0; i < 4; ++i) {
                __builtin_amdgcn_global_load_lds(
                    (const __attribute__((address_space(1))) u32*)(gsrc + i * 1024),
                    (__attribute__((address_space(3))) u32*)(ldst + i * 1024), 16, 0, 0);
            }
        }
        // prefetch x for chunk+1: its fb = ((chunk+1)-1)*16 = chunk*16
        f32x4 pfn = pf;
        if (chunk <= 7) pfn = *(const f32x4*)(ghr + chunk * 16 + gq * 4);

        if (chunk == 0) {
            // silu slots: thread covers features gq*32 .. gq*32+31
            f32x4 xv[8];
#pragma unroll
            for (int v = 0; v < 8; ++v) xv[v] = *(const f32x4*)(ghr + gq * 32 + v * 4);
#pragma unroll
            for (int sl = 0; sl < 4; ++sl) {
                int s = gq * 4 + sl;
                unsigned short pk[8];
#pragma unroll
                for (int j = 0; j < 4; ++j) {
                    pk[j] = f2bf(siluf(xv[2 * sl][j]));
                    pk[4 + j] = f2bf(siluf(xv[2 * sl + 1][j]));
                }
                *(bf16x8*)((char*)A_lds + gm * 256 + (((s ^ (gm & 7)) & 15) << 4)) =
                    *(bf16x8*)pk;
            }
        } else {
            // closed-form cardinal cubic B-spline on the uniform grid (see R4 notes)
#pragma unroll
            for (int j = 0; j < 4; ++j) {
                float x = pf[j];
                float t = (x + 2.2f) * 2.5f;
                float fl = floorf(t);
                int i0 = (int)fl;
                float u = t - fl;
                float um = 1.0f - u;
                float u2 = u * u, u3 = u2 * u;
                const float c6 = 1.0f / 6.0f;
                float w0 = um * um * um * c6;
                float w1 = (3.f * u3 - 6.f * u2 + 4.f) * c6;
                float w2 = (-3.f * u3 + 3.f * u2 + 3.f * u + 1.f) * c6;
                float w3 = u3 * c6;
                u64 Wp = (u64)f2bf(w0) | ((u64)f2bf(w1) << 16) |
                         ((u64)f2bf(w2) << 32) | ((u64)f2bf(w3) << 48);
                int sh = (i0 - 3) * 16;  // slot j0 = i0-3, 16 bits per bf16 slot
                u64 lo = 0, hi = 0;
                if (sh >= 0) {
                    if (sh < 64) {
                        lo = Wp << sh;
                        hi = sh ? (Wp >> (64 - sh)) : 0;
                    } else if (sh < 128) {
                        hi = Wp << (sh - 64);
                    }
                } else {
                    int r = -sh;
                    if (r < 64) lo = Wp >> r;
                }
                int s = gq * 4 + j;
                ulonglong2 pv; pv.x = lo; pv.y = hi;
                *(ulonglong2*)((char*)A_lds + gm * 256 + (((s ^ (gm & 7)) & 15) << 4)) = pv;
            }
        }
        __syncthreads();  // drains vmcnt (global_load_lds) + lgkm (ds_write)

        // MFMA: 4 k-steps of 32, 2x4 fragments per wave
#pragma unroll
        for (int kk = 0; kk < 4; ++kk) {
            bf16x8 af[2], bfr[4];
#pragma unroll
            for (int im = 0; im < 2; ++im) {
                int mrow = wm0 + im * 16 + (lane & 15);
                int slot = (kk * 4 + (lane >> 4)) ^ (mrow & 7);
                af[im] = *(const bf16x8*)((const char*)A_lds + mrow * 256 + slot * 16);
            }
#pragma unroll
            for (int in = 0; in < 4; ++in) {
                int orow = wn0 + in * 16 + (lane & 15);
                int slot = (kk * 4 + (lane >> 4)) ^ (orow & 7);
                bfr[in] = *(const bf16x8*)((const char*)B_lds + orow * 256 + slot * 16);
            }
#pragma unroll
            for (int im = 0; im < 2; ++im)
#pragma unroll
                for (int in = 0; in < 4; ++in)
                    acc[im][in] = __builtin_amdgcn_mfma_f32_16x16x32_bf16(
                        af[im], bfr[in], acc[im][in], 0, 0, 0);
        }
        __syncthreads();
        pf = pfn;
    }

    // batched score loads (issued early; latency hides under the epilogue)
    float wa0 = wa[lane], wa1 = wa[64 + lane];
    float wa2 = wa[128 + lane], wa3 = wa[192 + lane];
    float sx0[16], sx1[16];
    const int r0 = gm0 + wid * 16;
#pragma unroll
    for (int rr = 0; rr < 16; ++rr) {
        const float* hr = h + (size_t)min(r0 + rr, N - 1) * 128;
        sx0[rr] = hr[lane];
        sx1[rr] = hr[64 + lane];
    }

    // epilogue: acc -> bf16 via LDS (reuse A_lds), then vectorized global store.
#pragma unroll
    for (int im = 0; im < 2; ++im) {
        int rbase = wm0 + im * 16 + ((lane >> 4) << 2);
#pragma unroll
        for (int in = 0; in < 4; ++in) {
            int col = wn0 + in * 16 + (lane & 15);
#pragma unroll
            for (int r = 0; r < 4; ++r) {
                int row = rbase + r;
                int byte = row * 256 + ((col * 2) ^ (((row >> 2) & 3) << 5));
                *(unsigned short*)((char*)A_lds + byte) = f2bf(acc[im][in][r]);
            }
        }
    }
    __syncthreads();
    for (int i = tid; i < BM * 16; i += NTHR) {
        int row = i >> 4, s = i & 15;
        int byte = row * 256 + ((s << 4) ^ (((row >> 2) & 3) << 5));
        bf16x8 v = *(bf16x8*)((char*)A_lds + byte);
        int grow = gm0 + row;
        if (grow < N) *(bf16x8*)((char*)kanb + (size_t)grow * 256 + s * 16) = v;
    }

    // score reductions (16 independent shuffle-reduce chains)
#pragma unroll
    for (int rr = 0; rr < 16; ++rr) {
        float s1 = fmaf(sx0[rr], wa0, sx1[rr] * wa1);
        float s2 = fmaf(sx0[rr], wa2, sx1[rr] * wa3);
#pragma unroll
        for (int off = 32; off; off >>= 1) {
            s1 += __shfl_xor(s1, off, 64);
            s2 += __shfl_xor(s2, off, 64);
        }
        int grow = r0 + rr;
        if (lane == 0 && grow < N) {
            s_src[grow] = s1;
            s_dst[grow] = s2;
        }
    }
}

// ---------- coalesced scan (3 tiny kernels) ----------
__global__ void k_scan1(const int* __restrict__ counts, int* __restrict__ bsum, int N) {
    int tid = threadIdx.x;
    int idx = blockIdx.x * 256 + tid;
    int v = (idx < N) ? counts[idx] : 0;
#pragma unroll
    for (int off = 32; off; off >>= 1) v += __shfl_xor(v, off, 64);
    __shared__ int ws[4];
    if ((tid & 63) == 0) ws[tid >> 6] = v;
    __syncthreads();
    if (tid == 0) bsum[blockIdx.x] = ws[0] + ws[1] + ws[2] + ws[3];
}

__global__ __launch_bounds__(1024) void k_scan2(const int* __restrict__ bsum,
                                                int* __restrict__ ebase,
                                                int* __restrict__ offsN, int nb) {
    __shared__ int ws[16];
    __shared__ int tot;
    int tid = threadIdx.x;
    int lane = tid & 63, w = tid >> 6;
    int v = (tid < nb) ? bsum[tid] : 0;
    int inc = v;
#pragma unroll
    for (int off = 1; off < 64; off <<= 1) {
        int t = __shfl_up(inc, off, 64);
        if (lane >= off) inc += t;
    }
    if (lane == 63) ws[w] = inc;
    __syncthreads();
    if (w == 0 && lane < 16) {
        int x = ws[lane];
#pragma unroll
        for (int off = 1; off < 16; off <<= 1) {
            int t = __shfl_up(x, off, 64);
            if (lane >= off) x += t;
        }
        ws[lane] = x;
        if (lane == 15) tot = x;
    }
    __syncthreads();
    int wb = w ? ws[w - 1] : 0;
    if (tid < nb) ebase[tid] = wb + inc - v;  // exclusive
    if (tid == 0) offsN[0] = tot;
}

__global__ void k_scan3(const int* __restrict__ counts, const int* __restrict__ ebase,
                        int* __restrict__ offsets, int N) {
    int tid = threadIdx.x;
    int idx = blockIdx.x * 256 + tid;
    int v = (idx < N) ? counts[idx] : 0;
    int lane = tid & 63, w = tid >> 6;
    int inc = v;
#pragma unroll
    for (int off = 1; off < 64; off <<= 1) {
        int t = __shfl_up(inc, off, 64);
        if (lane >= off) inc += t;
    }
    __shared__ int ws[4];
    if (lane == 63) ws[w] = inc;
    __syncthreads();
    int wb = 0;
    for (int i = 0; i < w; ++i) wb += ws[i];
    if (idx < N) offsets[idx] = ebase[blockIdx.x] + wb + inc - v;
}

// ---------- per-row softmax + bf16 gather-sum, in-register canonical sort ----------
__global__ __launch_bounds__(256) void k_aggr(const int* __restrict__ offsets,
                                              int* __restrict__ cols,
                                              const float* __restrict__ s_src,
                                              const float* __restrict__ s_dst,
                                              const unsigned short* __restrict__ kanb,
                                              float* __restrict__ out, int N) {
    int wid = (blockIdx.x * 256 + threadIdx.x) >> 6;
    int lane = threadIdx.x & 63;
    if (wid >= N) return;
    int start = offsets[wid], end = offsets[wid + 1];
    int deg = end - start;
    float acc0 = 0.f, acc1 = 0.f;
    if (deg > 0) {
        float ssrc = s_src[wid];
        if (deg <= 64) {
            int key = 0x7fffffff;
            if (lane < deg) key = cols[start + lane];
            // 64-wide bitonic sort, ascending (canonical order -> determinism)
#pragma unroll
            for (int k = 2; k <= 64; k <<= 1) {
#pragma unroll
                for (int j = k >> 1; j > 0; j >>= 1) {
                    int other = __shfl_xor(key, j, 64);
                    bool asc = ((lane & k) == 0);
                    bool lowr = ((lane & j) == 0);
                    int mn = min(key, other), mx = max(key, other);
                    key = (asc == lowr) ? mn : mx;
                }
            }
            float e = -3.402823466e38f;
            if (lane < deg) {
                e = ssrc + s_dst[key];
                e = (e >= 0.f) ? e : 0.2f * e;
            }
            float m = e;
#pragma unroll
            for (int off = 32; off; off >>= 1) m = fmaxf(m, __shfl_xor(m, off, 64));
            float ex = (lane < deg) ? __expf(e - m) : 0.f;
            float s = ex;
#pragma unroll
            for (int off = 32; off; off >>= 1) s += __shfl_xor(s, off, 64);
            float att = ex / s;
            // software-pipelined gather: 16 row-loads in flight (covers median deg
            // in one batch; latency-bound phase — see R16 post-mortem)
            u32 pbuf[16];
            float wbuf[16];
#pragma unroll
            for (int t = 0; t < 16; ++t) {
                int qc = (t < deg) ? t : 0;
                int c = __shfl(key, qc, 64);
                wbuf[t] = (t < deg) ? __shfl(att, qc, 64) : 0.f;
                pbuf[t] = ((const u32*)(kanb + (size_t)c * 128))[lane];
            }
            for (int q0 = 0; q0 < deg; q0 += 16) {
                u32 pc[16];
                float wc[16];
#pragma unroll
                for (int t = 0; t < 16; ++t) { pc[t] = pbuf[t]; wc[t] = wbuf[t]; }
                if (q0 + 16 < deg) {  // wave-uniform guard
#pragma unroll
                    for (int t = 0; t < 16; ++t) {
                        int q = q0 + 16 + t;
                        int qc = (q < deg) ? q : 0;
                        int c = __shfl(key, qc, 64);
                        wbuf[t] = (q < deg) ? __shfl(att, qc, 64) : 0.f;
                        pbuf[t] = ((const u32*)(kanb + (size_t)c * 128))[lane];
                    }
                }
#pragma unroll
                for (int t = 0; t < 16; ++t) {
                    float lo = __builtin_bit_cast(float, pc[t] << 16);
                    float hi = __builtin_bit_cast(float, pc[t] & 0xffff0000u);
                    acc0 = fmaf(wc[t], lo, acc0);
                    acc1 = fmaf(wc[t], hi, acc1);
                }
            }
        } else {
            // rare fallback: lane0 insertion-sorts the segment in place, then memory path
            if (lane == 0) {
                for (int i = start + 1; i < end; ++i) {
                    int v = cols[i];
                    int j = i - 1;
                    while (j >= start && cols[j] > v) { cols[j + 1] = cols[j]; --j; }
                    cols[j + 1] = v;
                }
            }
            __threadfence();
            float m = -3.402823466e38f;
            for (int j = start + lane; j < end; j += 64) {
                float e = ssrc + s_dst[cols[j]];
                e = (e >= 0.f) ? e : 0.2f * e;
                m = fmaxf(m, e);
            }
#pragma unroll
            for (int off = 32; off; off >>= 1) m = fmaxf(m, __shfl_xor(m, off, 64));
            float s = 0.f;
            for (int j = start + lane; j < end; j += 64) {
                float e = ssrc + s_dst[cols[j]];
                e = (e >= 0.f) ? e : 0.2f * e;
                s += __expf(e - m);
            }
#pragma unroll
            for (int off = 32; off; off >>= 1) s += __shfl_xor(s, off, 64);
            float inv = 1.0f / s;
            for (int t = start; t < end; t += 64) {
                int j = t + lane;
                float att = 0.f;
                int myc = 0;
                if (j < end) {
                    myc = cols[j];
                    float e = ssrc + s_dst[myc];
                    e = (e >= 0.f) ? e : 0.2f * e;
                    att = __expf(e - m) * inv;
                }
                int cnt = min(64, end - t);
                for (int q = 0; q < cnt; ++q) {
                    float w = __shfl(att, q, 64);
                    int c = __shfl(myc, q, 64);
                    u32 p = ((const u32*)(kanb + (size_t)c * 128))[lane];
                    float lo = __builtin_bit_cast(float, p << 16);
                    float hi = __builtin_bit_cast(float, p & 0xffff0000u);
                    acc0 = fmaf(w, lo, acc0);
                    acc1 = fmaf(w, hi, acc1);
                }
            }
        }
    }
    // nontemporal out store: written once, never re-read
    u64 pv = (u64)__builtin_bit_cast(u32, acc0) | ((u64)__builtin_bit_cast(u32, acc1) << 32);
    __builtin_nontemporal_store(pv, (u64*)(out + (size_t)wid * 128 + lane * 2));
}

extern "C" void kernel_launch(void* const* d_in, const int* in_sizes, int n_in,
                              void* d_out, int out_size, void* d_ws, size_t ws_size,
                              hipStream_t stream) {
    const float* h  = (const float*)d_in[0];
    const int*   ei = (const int*)d_in[1];
    const float* W  = (const float*)d_in[2];
    const float* a  = (const float*)d_in[3];
    const float* bw = (const float*)d_in[4];
    const float* sw = (const float*)d_in[5];
    float* out = (float*)d_out;
    const int N = in_sizes[0] / 128;
    const int E = in_sizes[1] / 2;
    const int nb = (N + 255) / 256;
    const int nbn = (N + BM - 1) / BM;              // node tiles
    const int nbuk = (N + 255) >> 8;                // buckets (256 rows each)
    const int per = (E + PHA - 1) / PHA;            // edges per phase-A block

    char* ws = (char*)d_ws;
    auto alloc = [&](size_t bytes) {
        char* p = ws;
        ws += (bytes + 255) & ~(size_t)255;
        return p;
    };
    unsigned short* Bsw = (unsigned short*)alloc((size_t)NCHUNK * 128 * 128 * 2);
    float* wa    = (float*)alloc(256 * 4);
    float* ssrc  = (float*)alloc((size_t)N * 4);
    float* sdst  = (float*)alloc((size_t)N * 4);
    unsigned short* kanb = (unsigned short*)alloc((size_t)N * 128 * 2);
    int* counts  = (int*)alloc((size_t)N * 4);
    int* offsets = (int*)alloc(((size_t)N + 1) * 4);
    int* colss   = (int*)alloc((size_t)E * 4);
    u32* binned  = (u32*)alloc((size_t)nbuk * PHA * PERBK * 4);
    int* pbcnt   = (int*)alloc((size_t)nbuk * PHA * 4);  // fully written by phase A
    int* bsum    = (int*)alloc((size_t)nb * 4);
    int* ebase   = (int*)alloc((size_t)nb * 4);

    hipMemsetAsync(counts, 0, (size_t)N * 4, stream);

    k_prep<<<PREPB + 1 + PHA, 256, 0, stream>>>(bw, sw, W, a, Bsw, wa,
                                                ei, ei + E, counts, binned, pbcnt,
                                                E, nbuk, per);
    k_scan1<<<nb, 256, 0, stream>>>(counts, bsum, N);
    k_scan2<<<1, 1024, 0, stream>>>(bsum, ebase, offsets + N, nb);
    k_scan3<<<nb, 256, 0, stream>>>(counts, ebase, offsets, N);
    k_nodes<<<nbn + nbuk, NTHR, 0, stream>>>(h, Bsw, wa, kanb, ssrc, sdst, N, nbn,
                                             binned, pbcnt, offsets, colss);
    k_aggr<<<(N + 3) / 4, 256, 0, stream>>>(offsets, colss, ssrc, sdst, kanb, out, N);
}

// Round 18
// 141.661 us; speedup vs baseline: 1.1206x; 1.1206x over previous
//
#include <hip/hip_runtime.h>
#include <hip/hip_bf16.h>
#include <math.h>

#define NCHUNK 9
#define BM 128
#define NTHR 512
#define PREPB ((NCHUNK * 128 * 128) / 256)  // 576 Bsw blocks
#define PHA 256        // phase-A binning blocks
#define PERBK 48       // per-(block,bucket) capacity: mean 16, +8 sigma
#define NBUKMAX 512    // LDS counter bound (N <= 131072)

typedef __attribute__((ext_vector_type(4))) float f32x4;
typedef __attribute__((ext_vector_type(8))) short bf16x8;
typedef unsigned int u32;
typedef unsigned long long u64;

__device__ __forceinline__ unsigned short f2bf(float f) {
    u32 u = __builtin_bit_cast(u32, f);
    u32 r = (u + 0x7FFFu + ((u >> 16) & 1u)) >> 16;
    return (unsigned short)r;
}

__device__ __forceinline__ float siluf(float x) {
    return x / (1.0f + __expf(-x));
}

// ---------- merged prep: Bsw build (swizzled) + wa + {hist + LDS-counted binning} ----------
__global__ void k_prep(const float* __restrict__ bw, const float* __restrict__ sw,
                       const float* __restrict__ W, const float* __restrict__ a,
                       unsigned short* __restrict__ Bsw, float* __restrict__ wa,
                       const int* __restrict__ erow, const int* __restrict__ ecol,
                       int* __restrict__ counts, u32* __restrict__ binned,
                       int* __restrict__ pbcnt, int E, int nbuk, int per) {
    int bid = blockIdx.x;
    if (bid < PREPB) {
        int i = bid * 256 + threadIdx.x;
        int j = i & 7;
        int s = (i >> 3) & 15;
        int o = (i >> 7) & 127;
        int c = i >> 14;
        int k = c * 128 + (((s ^ (o & 7)) << 3) | j);
        float v = (k < 128) ? bw[o * 128 + k] : sw[o * 1024 + (k - 128)];
        Bsw[i] = f2bf(v);
        return;
    }
    if (bid == PREPB) {
        int fi = threadIdx.x;
        if (fi < 128) {
            float s1 = 0.f, s2 = 0.f;
            for (int o = 0; o < 128; ++o) {
                float w = W[fi * 128 + o];
                s1 = fmaf(w, a[o], s1);
                s2 = fmaf(w, a[128 + o], s2);
            }
            wa[fi] = s1;
            wa[128 + fi] = s2;
        }
        return;
    }
    // ---- phase-A binning + hist ----
    __shared__ int cnt[NBUKMAX];
    int pb = bid - PREPB - 1;  // 0..PHA-1
    int e0 = pb * per;
    int e1 = min(e0 + per, E);
    for (int i = threadIdx.x; i < nbuk; i += 256) cnt[i] = 0;
    __syncthreads();
    for (int e = e0 + threadIdx.x; e < e1; e += 256) {
        int r = erow[e], c = ecol[e];
        atomicAdd(&counts[r], 1);
        int b = r >> 8;
        int pos = atomicAdd(&cnt[b], 1);
        if (pos < PERBK)  // statistically unreachable (+8 sigma)
            binned[(size_t)b * (PHA * PERBK) + pb * PERBK + pos] =
                ((u32)c << 8) | (u32)(r & 255);
    }
    __syncthreads();
    for (int i = threadIdx.x; i < nbuk; i += 256)
        pbcnt[(size_t)i * PHA + pb] = min(cnt[i], PERBK);
}

// ---------- main node kernel: 128x128 bf16 MFMA GEMM + fused scores + phase-B drain ----------
__global__ __launch_bounds__(NTHR) void k_nodes(const float* __restrict__ h,
                                                const unsigned short* __restrict__ Bsw,
                                                const float* __restrict__ wa,
                                                unsigned short* __restrict__ kanb,
                                                float* __restrict__ s_src,
                                                float* __restrict__ s_dst, int N, int nbn,
                                                const u32* __restrict__ binned,
                                                const int* __restrict__ pbcnt,
                                                const int* __restrict__ offsets,
                                                int* __restrict__ colss) {
    __shared__ unsigned short A_lds[BM * 128];  // 32 KB, XOR-swizzled (reused for C out)
    __shared__ unsigned short B_lds[128 * 128]; // 32 KB, XOR-swizzled (pre-swz global)
    __shared__ int lcur[256];                   // phase-B row cursors (LDS atomics)
    __shared__ int scnt[PHA];                   // phase-B per-segment counts
    const int tid = threadIdx.x;
    const int wid = tid >> 6, lane = tid & 63;

    if (blockIdx.x >= nbn) {  // ---- phase-B bucket-drain blocks ----
        int b = blockIdx.x - nbn;
        int rowbase = b << 8;
        for (int i = tid; i < 256; i += NTHR) {
            int r = rowbase + i;
            lcur[i] = (r < N) ? offsets[r] : 0;
        }
        for (int pb = tid; pb < PHA; pb += NTHR) scnt[pb] = pbcnt[(size_t)b * PHA + pb];
        __syncthreads();
        const u32* src = binned + (size_t)b * (PHA * PERBK);
        for (int pb = wid; pb < PHA; pb += 8) {  // 8 waves, 32 segments each
            int n = scnt[pb];
            if (lane < n) {
                u32 pk = src[pb * PERBK + lane];
                int pos = atomicAdd(&lcur[pk & 255u], 1);  // LDS atomic
                __builtin_nontemporal_store((int)(pk >> 8), &colss[pos]);
            }
        }
        return;
    }

    const int gm0 = blockIdx.x * BM;

    // gen mapping: thread owns (row gm, slot-quad gq) — 4 slots of 8 features
    const int gm = tid >> 2, gq = tid & 3;
    const float* ghr = h + (size_t)min(gm0 + gm, N - 1) * 128;

    const int wm0 = (wid >> 1) * 32;  // wave row offset within tile (8 waves: 4m x 2n)
    const int wn0 = (wid & 1) * 64;   // wave col offset
    f32x4 acc[2][4];
#pragma unroll
    for (int im = 0; im < 2; ++im)
#pragma unroll
        for (int in = 0; in < 4; ++in) acc[im][in] = {0.f, 0.f, 0.f, 0.f};

    f32x4 pf = {0.f, 0.f, 0.f, 0.f};  // spline x for current chunk (valid for chunk>=1)
    for (int chunk = 0; chunk < NCHUNK; ++chunk) {
        // async-stage B chunk (32 KB): each of 8 waves copies its 4 KB segment
        {
            const char* gsrc = (const char*)Bsw + (size_t)chunk * 32768 + wid * 4096 + lane * 16;
            char* ldst = (char*)B_lds + wid * 4096;
#pragma unroll
            for (int i = 0; i < 4; ++i) {
                __builtin_amdgcn_global_load_lds(
                    (const __attribute__((address_space(1))) u32*)(gsrc + i * 1024),
                    (__attribute__((address_space(3))) u32*)(ldst + i * 1024), 16, 0, 0);
            }
        }
        // prefetch x for chunk+1: its fb = ((chunk+1)-1)*16 = chunk*16
        f32x4 pfn = pf;
        if (chunk <= 7) pfn = *(const f32x4*)(ghr + chunk * 16 + gq * 4);

        if (chunk == 0) {
            // silu slots: thread covers features gq*32 .. gq*32+31
            f32x4 xv[8];
#pragma unroll
            for (int v = 0; v < 8; ++v) xv[v] = *(const f32x4*)(ghr + gq * 32 + v * 4);
#pragma unroll
            for (int sl = 0; sl < 4; ++sl) {
                int s = gq * 4 + sl;
                unsigned short pk[8];
#pragma unroll
                for (int j = 0; j < 4; ++j) {
                    pk[j] = f2bf(siluf(xv[2 * sl][j]));
                    pk[4 + j] = f2bf(siluf(xv[2 * sl + 1][j]));
                }
                *(bf16x8*)((char*)A_lds + gm * 256 + (((s ^ (gm & 7)) & 15) << 4)) =
                    *(bf16x8*)pk;
            }
        } else {
            // closed-form cardinal cubic B-spline on the uniform grid (see R4 notes)
#pragma unroll
            for (int j = 0; j < 4; ++j) {
                float x = pf[j];
                float t = (x + 2.2f) * 2.5f;
                float fl = floorf(t);
                int i0 = (int)fl;
                float u = t - fl;
                float um = 1.0f - u;
                float u2 = u * u, u3 = u2 * u;
                const float c6 = 1.0f / 6.0f;
                float w0 = um * um * um * c6;
                float w1 = (3.f * u3 - 6.f * u2 + 4.f) * c6;
                float w2 = (-3.f * u3 + 3.f * u2 + 3.f * u + 1.f) * c6;
                float w3 = u3 * c6;
                u64 Wp = (u64)f2bf(w0) | ((u64)f2bf(w1) << 16) |
                         ((u64)f2bf(w2) << 32) | ((u64)f2bf(w3) << 48);
                int sh = (i0 - 3) * 16;  // slot j0 = i0-3, 16 bits per bf16 slot
                u64 lo = 0, hi = 0;
                if (sh >= 0) {
                    if (sh < 64) {
                        lo = Wp << sh;
                        hi = sh ? (Wp >> (64 - sh)) : 0;
                    } else if (sh < 128) {
                        hi = Wp << (sh - 64);
                    }
                } else {
                    int r = -sh;
                    if (r < 64) lo = Wp >> r;
                }
                int s = gq * 4 + j;
                ulonglong2 pv; pv.x = lo; pv.y = hi;
                *(ulonglong2*)((char*)A_lds + gm * 256 + (((s ^ (gm & 7)) & 15) << 4)) = pv;
            }
        }
        __syncthreads();  // drains vmcnt (global_load_lds) + lgkm (ds_write)

        // MFMA: 4 k-steps of 32, 2x4 fragments per wave
#pragma unroll
        for (int kk = 0; kk < 4; ++kk) {
            bf16x8 af[2], bfr[4];
#pragma unroll
            for (int im = 0; im < 2; ++im) {
                int mrow = wm0 + im * 16 + (lane & 15);
                int slot = (kk * 4 + (lane >> 4)) ^ (mrow & 7);
                af[im] = *(const bf16x8*)((const char*)A_lds + mrow * 256 + slot * 16);
            }
#pragma unroll
            for (int in = 0; in < 4; ++in) {
                int orow = wn0 + in * 16 + (lane & 15);
                int slot = (kk * 4 + (lane >> 4)) ^ (orow & 7);
                bfr[in] = *(const bf16x8*)((const char*)B_lds + orow * 256 + slot * 16);
            }
#pragma unroll
            for (int im = 0; im < 2; ++im)
#pragma unroll
                for (int in = 0; in < 4; ++in)
                    acc[im][in] = __builtin_amdgcn_mfma_f32_16x16x32_bf16(
                        af[im], bfr[in], acc[im][in], 0, 0, 0);
        }
        __syncthreads();
        pf = pfn;
    }

    // batched score loads (issued early; latency hides under the epilogue)
    float wa0 = wa[lane], wa1 = wa[64 + lane];
    float wa2 = wa[128 + lane], wa3 = wa[192 + lane];
    float sx0[16], sx1[16];
    const int r0 = gm0 + wid * 16;
#pragma unroll
    for (int rr = 0; rr < 16; ++rr) {
        const float* hr = h + (size_t)min(r0 + rr, N - 1) * 128;
        sx0[rr] = hr[lane];
        sx1[rr] = hr[64 + lane];
    }

    // epilogue: acc -> bf16 via LDS (reuse A_lds), then vectorized global store.
#pragma unroll
    for (int im = 0; im < 2; ++im) {
        int rbase = wm0 + im * 16 + ((lane >> 4) << 2);
#pragma unroll
        for (int in = 0; in < 4; ++in) {
            int col = wn0 + in * 16 + (lane & 15);
#pragma unroll
            for (int r = 0; r < 4; ++r) {
                int row = rbase + r;
                int byte = row * 256 + ((col * 2) ^ (((row >> 2) & 3) << 5));
                *(unsigned short*)((char*)A_lds + byte) = f2bf(acc[im][in][r]);
            }
        }
    }
    __syncthreads();
    for (int i = tid; i < BM * 16; i += NTHR) {
        int row = i >> 4, s = i & 15;
        int byte = row * 256 + ((s << 4) ^ (((row >> 2) & 3) << 5));
        bf16x8 v = *(bf16x8*)((char*)A_lds + byte);
        int grow = gm0 + row;
        if (grow < N) *(bf16x8*)((char*)kanb + (size_t)grow * 256 + s * 16) = v;
    }

    // score reductions (16 independent shuffle-reduce chains)
#pragma unroll
    for (int rr = 0; rr < 16; ++rr) {
        float s1 = fmaf(sx0[rr], wa0, sx1[rr] * wa1);
        float s2 = fmaf(sx0[rr], wa2, sx1[rr] * wa3);
#pragma unroll
        for (int off = 32; off; off >>= 1) {
            s1 += __shfl_xor(s1, off, 64);
            s2 += __shfl_xor(s2, off, 64);
        }
        int grow = r0 + rr;
        if (lane == 0 && grow < N) {
            s_src[grow] = s1;
            s_dst[grow] = s2;
        }
    }
}

// ---------- coalesced scan (3 tiny kernels) ----------
__global__ void k_scan1(const int* __restrict__ counts, int* __restrict__ bsum, int N) {
    int tid = threadIdx.x;
    int idx = blockIdx.x * 256 + tid;
    int v = (idx < N) ? counts[idx] : 0;
#pragma unroll
    for (int off = 32; off; off >>= 1) v += __shfl_xor(v, off, 64);
    __shared__ int ws[4];
    if ((tid & 63) == 0) ws[tid >> 6] = v;
    __syncthreads();
    if (tid == 0) bsum[blockIdx.x] = ws[0] + ws[1] + ws[2] + ws[3];
}

__global__ __launch_bounds__(1024) void k_scan2(const int* __restrict__ bsum,
                                                int* __restrict__ ebase,
                                                int* __restrict__ offsN, int nb) {
    __shared__ int ws[16];
    __shared__ int tot;
    int tid = threadIdx.x;
    int lane = tid & 63, w = tid >> 6;
    int v = (tid < nb) ? bsum[tid] : 0;
    int inc = v;
#pragma unroll
    for (int off = 1; off < 64; off <<= 1) {
        int t = __shfl_up(inc, off, 64);
        if (lane >= off) inc += t;
    }
    if (lane == 63) ws[w] = inc;
    __syncthreads();
    if (w == 0 && lane < 16) {
        int x = ws[lane];
#pragma unroll
        for (int off = 1; off < 16; off <<= 1) {
            int t = __shfl_up(x, off, 64);
            if (lane >= off) x += t;
        }
        ws[lane] = x;
        if (lane == 15) tot = x;
    }
    __syncthreads();
    int wb = w ? ws[w - 1] : 0;
    if (tid < nb) ebase[tid] = wb + inc - v;  // exclusive
    if (tid == 0) offsN[0] = tot;
}

__global__ void k_scan3(const int* __restrict__ counts, const int* __restrict__ ebase,
                        int* __restrict__ offsets, int N) {
    int tid = threadIdx.x;
    int idx = blockIdx.x * 256 + tid;
    int v = (idx < N) ? counts[idx] : 0;
    int lane = tid & 63, w = tid >> 6;
    int inc = v;
#pragma unroll
    for (int off = 1; off < 64; off <<= 1) {
        int t = __shfl_up(inc, off, 64);
        if (lane >= off) inc += t;
    }
    __shared__ int ws[4];
    if (lane == 63) ws[w] = inc;
    __syncthreads();
    int wb = 0;
    for (int i = 0; i < w; ++i) wb += ws[i];
    if (idx < N) offsets[idx] = ebase[blockIdx.x] + wb + inc - v;
}

// ---------- per-row softmax + bf16 gather-sum, in-register canonical sort ----------
__global__ __launch_bounds__(256) void k_aggr(const int* __restrict__ offsets,
                                              int* __restrict__ cols,
                                              const float* __restrict__ s_src,
                                              const float* __restrict__ s_dst,
                                              const unsigned short* __restrict__ kanb,
                                              float* __restrict__ out, int N) {
    int wid = (blockIdx.x * 256 + threadIdx.x) >> 6;
    int lane = threadIdx.x & 63;
    if (wid >= N) return;
    int start = offsets[wid], end = offsets[wid + 1];
    int deg = end - start;
    float acc0 = 0.f, acc1 = 0.f;
    if (deg > 0) {
        float ssrc = s_src[wid];
        if (deg <= 64) {
            int key = 0x7fffffff;
            if (lane < deg) key = cols[start + lane];
            // 64-wide bitonic sort, ascending (canonical order -> determinism)
#pragma unroll
            for (int k = 2; k <= 64; k <<= 1) {
#pragma unroll
                for (int j = k >> 1; j > 0; j >>= 1) {
                    int other = __shfl_xor(key, j, 64);
                    bool asc = ((lane & k) == 0);
                    bool lowr = ((lane & j) == 0);
                    int mn = min(key, other), mx = max(key, other);
                    key = (asc == lowr) ? mn : mx;
                }
            }
            float e = -3.402823466e38f;
            if (lane < deg) {
                e = ssrc + s_dst[key];
                e = (e >= 0.f) ? e : 0.2f * e;
            }
            float m = e;
#pragma unroll
            for (int off = 32; off; off >>= 1) m = fmaxf(m, __shfl_xor(m, off, 64));
            float ex = (lane < deg) ? __expf(e - m) : 0.f;
            float s = ex;
#pragma unroll
            for (int off = 32; off; off >>= 1) s += __shfl_xor(s, off, 64);
            float att = ex / s;
            // software-pipelined gather: 8 row-loads in flight
            u32 pbuf[8];
            float wbuf[8];
#pragma unroll
            for (int t = 0; t < 8; ++t) {
                int qc = (t < deg) ? t : 0;
                int c = __shfl(key, qc, 64);
                wbuf[t] = (t < deg) ? __shfl(att, qc, 64) : 0.f;
                pbuf[t] = ((const u32*)(kanb + (size_t)c * 128))[lane];
            }
            for (int q0 = 0; q0 < deg; q0 += 8) {
                u32 pc[8];
                float wc[8];
#pragma unroll
                for (int t = 0; t < 8; ++t) { pc[t] = pbuf[t]; wc[t] = wbuf[t]; }
                if (q0 + 8 < deg) {  // wave-uniform guard
#pragma unroll
                    for (int t = 0; t < 8; ++t) {
                        int q = q0 + 8 + t;
                        int qc = (q < deg) ? q : 0;
                        int c = __shfl(key, qc, 64);
                        wbuf[t] = (q < deg) ? __shfl(att, qc, 64) : 0.f;
                        pbuf[t] = ((const u32*)(kanb + (size_t)c * 128))[lane];
                    }
                }
#pragma unroll
                for (int t = 0; t < 8; ++t) {
                    float lo = __builtin_bit_cast(float, pc[t] << 16);
                    float hi = __builtin_bit_cast(float, pc[t] & 0xffff0000u);
                    acc0 = fmaf(wc[t], lo, acc0);
                    acc1 = fmaf(wc[t], hi, acc1);
                }
            }
        } else {
            // rare fallback: lane0 insertion-sorts the segment in place, then memory path
            if (lane == 0) {
                for (int i = start + 1; i < end; ++i) {
                    int v = cols[i];
                    int j = i - 1;
                    while (j >= start && cols[j] > v) { cols[j + 1] = cols[j]; --j; }
                    cols[j + 1] = v;
                }
            }
            __threadfence();
            float m = -3.402823466e38f;
            for (int j = start + lane; j < end; j += 64) {
                float e = ssrc + s_dst[cols[j]];
                e = (e >= 0.f) ? e : 0.2f * e;
                m = fmaxf(m, e);
            }
#pragma unroll
            for (int off = 32; off; off >>= 1) m = fmaxf(m, __shfl_xor(m, off, 64));
            float s = 0.f;
            for (int j = start + lane; j < end; j += 64) {
                float e = ssrc + s_dst[cols[j]];
                e = (e >= 0.f) ? e : 0.2f * e;
                s += __expf(e - m);
            }
#pragma unroll
            for (int off = 32; off; off >>= 1) s += __shfl_xor(s, off, 64);
            float inv = 1.0f / s;
            for (int t = start; t < end; t += 64) {
                int j = t + lane;
                float att = 0.f;
                int myc = 0;
                if (j < end) {
                    myc = cols[j];
                    float e = ssrc + s_dst[myc];
                    e = (e >= 0.f) ? e : 0.2f * e;
                    att = __expf(e - m) * inv;
                }
                int cnt = min(64, end - t);
                for (int q = 0; q < cnt; ++q) {
                    float w = __shfl(att, q, 64);
                    int c = __shfl(myc, q, 64);
                    u32 p = ((const u32*)(kanb + (size_t)c * 128))[lane];
                    float lo = __builtin_bit_cast(float, p << 16);
                    float hi = __builtin_bit_cast(float, p & 0xffff0000u);
                    acc0 = fmaf(w, lo, acc0);
                    acc1 = fmaf(w, hi, acc1);
                }
            }
        }
    }
    // nontemporal out store: written once, never re-read
    u64 pv = (u64)__builtin_bit_cast(u32, acc0) | ((u64)__builtin_bit_cast(u32, acc1) << 32);
    __builtin_nontemporal_store(pv, (u64*)(out + (size_t)wid * 128 + lane * 2));
}

extern "C" void kernel_launch(void* const* d_in, const int* in_sizes, int n_in,
                              void* d_out, int out_size, void* d_ws, size_t ws_size,
                              hipStream_t stream) {
    const float* h  = (const float*)d_in[0];
    const int*   ei = (const int*)d_in[1];
    const float* W  = (const float*)d_in[2];
    const float* a  = (const float*)d_in[3];
    const float* bw = (const float*)d_in[4];
    const float* sw = (const float*)d_in[5];
    float* out = (float*)d_out;
    const int N = in_sizes[0] / 128;
    const int E = in_sizes[1] / 2;
    const int nb = (N + 255) / 256;
    const int nbn = (N + BM - 1) / BM;              // node tiles
    const int nbuk = (N + 255) >> 8;                // buckets (256 rows each)
    const int per = (E + PHA - 1) / PHA;            // edges per phase-A block

    char* ws = (char*)d_ws;
    auto alloc = [&](size_t bytes) {
        char* p = ws;
        ws += (bytes + 255) & ~(size_t)255;
        return p;
    };
    unsigned short* Bsw = (unsigned short*)alloc((size_t)NCHUNK * 128 * 128 * 2);
    float* wa    = (float*)alloc(256 * 4);
    float* ssrc  = (float*)alloc((size_t)N * 4);
    float* sdst  = (float*)alloc((size_t)N * 4);
    unsigned short* kanb = (unsigned short*)alloc((size_t)N * 128 * 2);
    int* counts  = (int*)alloc((size_t)N * 4);
    int* offsets = (int*)alloc(((size_t)N + 1) * 4);
    int* colss   = (int*)alloc((size_t)E * 4);
    u32* binned  = (u32*)alloc((size_t)nbuk * PHA * PERBK * 4);
    int* pbcnt   = (int*)alloc((size_t)nbuk * PHA * 4);  // fully written by phase A
    int* bsum    = (int*)alloc((size_t)nb * 4);
    int* ebase   = (int*)alloc((size_t)nb * 4);

    hipMemsetAsync(counts, 0, (size_t)N * 4, stream);

    k_prep<<<PREPB + 1 + PHA, 256, 0, stream>>>(bw, sw, W, a, Bsw, wa,
                                                ei, ei + E, counts, binned, pbcnt,
                                                E, nbuk, per);
    k_scan1<<<nb, 256, 0, stream>>>(counts, bsum, N);
    k_scan2<<<1, 1024, 0, stream>>>(bsum, ebase, offsets + N, nb);
    k_scan3<<<nb, 256, 0, stream>>>(counts, ebase, offsets, N);
    k_nodes<<<nbn + nbuk, NTHR, 0, stream>>>(h, Bsw, wa, kanb, ssrc, sdst, N, nbn,
                                             binned, pbcnt, offsets, colss);
    k_aggr<<<(N + 3) / 4, 256, 0, stream>>>(offsets, colss, ssrc, sdst, kanb, out, N);
}